// Round 14
// baseline (45.382 us; speedup 1.0000x reference)
//
#include <hip/hip_runtime.h>
#include <hip/hip_bf16.h>
#include <cstdint>

#define NN 8192
#define DD 512
#define NC 128      // number of classes

typedef unsigned short u16;
typedef __attribute__((ext_vector_type(8))) short short8;
typedef __attribute__((ext_vector_type(4))) float f32x4;

#define AS1 __attribute__((address_space(1)))
#define AS3 __attribute__((address_space(3)))

// workspace layout (bytes)
#define FB_OFF   ((size_t)0)                      // bf16 features: NN*DD*2 = 8 MB
#define SQ_OFF   (FB_OFF + (size_t)NN*DD*2)       // fp32 sq norms: NN*4
#define ND_OFF   (SQ_OFF + (size_t)NN*4)          // fp32 neg_dist: NN*4
#define ACC_OFF  (ND_OFF + (size_t)NN*4)          // total(f32)@+0, cnt(int)@+4, done(int)@+8
#define CC_OFF   (ACC_OFF + 64)                   // class counts: NC*4
#define POS_OFF  (CC_OFF + 1024)                  // ordered member positions: NC*128*4

// ---- K1: fused {per-class positions + k-th negative + nd} | {prep} -------
// blocks 0..127   : class c = blockIdx.x — classpos scan (two-pass, verified
//                   r12 k_pos), then per-member ballot-rank + DISTRIBUTED
//                   fp32 nd-dots (4 threads/member -> 256 independent load
//                   streams, no serial gather chains — the r10 lesson).
// blocks 128..2175: prep (r13 verbatim): sq norms + bf16 cast of 4 rows.
// NO atomics anywhere in this kernel -> plain-store zeroing of the
// accumulator line (block 0) is flushed at kernel end, before k_cls's
// atomics touch it (r9-verified pattern).
__global__ __launch_bounds__(256) void k_pn(const float* __restrict__ F,
    const int* __restrict__ labels, const float* __restrict__ negu,
    u16* __restrict__ Fb, float* __restrict__ sq, int* __restrict__ cc,
    int* __restrict__ pos, float* __restrict__ nd, int* __restrict__ accz) {
  const int wid = threadIdx.x >> 6, lane = threadIdx.x & 63;
  if (blockIdx.x >= NC) {                // ---------------- prep half
    const int row = (blockIdx.x - NC) * 4 + wid;
    const float* fr = F + (size_t)row * DD + lane * 8;
    float4 v0 = *(const float4*)fr;
    float4 v1 = *(const float4*)(fr + 4);
    float s = v0.x*v0.x + v0.y*v0.y + v0.z*v0.z + v0.w*v0.w
            + v1.x*v1.x + v1.y*v1.y + v1.z*v1.z + v1.w*v1.w;
    #pragma unroll
    for (int o = 32; o; o >>= 1) s += __shfl_xor(s, o);
    float t[8] = {v0.x, v0.y, v0.z, v0.w, v1.x, v1.y, v1.z, v1.w};
    unsigned p[8];
    #pragma unroll
    for (int e = 0; e < 8; ++e) {   // RNE fp32->bf16
      unsigned b = __float_as_uint(t[e]);
      b += 0x7fffu + ((b >> 16) & 1u);
      p[e] = b >> 16;
    }
    uint4 w;
    w.x = p[0] | (p[1] << 16); w.y = p[2] | (p[3] << 16);
    w.z = p[4] | (p[5] << 16); w.w = p[6] | (p[7] << 16);
    *(uint4*)(Fb + (size_t)row * DD + lane * 8) = w;
    if (lane == 0) sq[row] = s;
  } else {                               // ------- per-class pos + neg + nd
    const int c = blockIdx.x;
    if (c == 0 && threadIdx.x < 16) accz[threadIdx.x] = 0;
    __shared__ int wcnt[4], woff[4], ncs;
    __shared__ int posc[128], jm[128];
    __shared__ float pd[128][4], psi[128][4], psj[128][4];
    const int base0 = wid * 2048;
    int cw = 0;
    for (int b = 0; b < 2048; b += 64)   // pass 1: count
      cw += __popcll(__ballot(labels[base0 + b + lane] == c));
    if (lane == 0) wcnt[wid] = cw;
    __syncthreads();
    if (threadIdx.x == 0) {
      int o = 0;
      #pragma unroll
      for (int w = 0; w < 4; ++w) { woff[w] = o; o += wcnt[w]; }
      cc[c] = o; ncs = o;
    }
    __syncthreads();
    int off = woff[wid];
    for (int b = 0; b < 2048; b += 64) { // pass 2: emit (ascending order)
      const int idx = base0 + b + lane;
      const int hit = (labels[idx] == c);
      const unsigned long long m = __ballot(hit);
      if (hit) {
        const int slot = off + __popcll(m & ((1ull << lane) - 1ull));
        pos[c * 128 + slot] = idx;
        posc[slot] = idx;
      }
      off += __popcll(m);
    }
    __syncthreads();
    const int nc = ncs;
    for (int t = nc + threadIdx.x; t < 128; t += 256) {
      pos[c * 128 + t] = 0; posc[t] = 0;       // pad
    }
    __syncthreads();
    const int n_neg = NN - nc;
    if (n_neg <= 0) {                          // unreachable for this data
      for (int m = threadIdx.x; m < nc; m += 256) nd[posc[m]] = __builtin_inff();
      return;
    }
    // rank per member: posc ascending => posc[t]-t non-decreasing;
    // t* = #{t: posc[t]-t <= k}; j = k + t*   (verified r5..r13 formula)
    const int p0 = posc[lane], p1 = posc[64 + lane];
    for (int m = wid; m < nc; m += 4) {
      const int i = posc[m];
      int k = (int)floorf(negu[i] * (float)n_neg);  // exact fp32 replica of ref
      k = k < 0 ? 0 : (k > n_neg - 1 ? n_neg - 1 : k);
      const int t = __popcll(__ballot((lane < nc) && (p0 - lane <= k)))
                  + __popcll(__ballot((64 + lane < nc) && (p1 - (64 + lane) <= k)));
      if (lane == 0) jm[m] = k + t;
    }
    __syncthreads();
    // distributed fp32 dots: thread = (member, quarter); independent streams
    const int mq = threadIdx.x >> 2, q = threadIdx.x & 3;
    for (int m = mq; m < nc; m += 64) {
      const float* fi = F + (size_t)posc[m] * DD + q * 128;
      const float* fj = F + (size_t)jm[m]   * DD + q * 128;
      float d = 0.0f, si = 0.0f, sj = 0.0f;
      #pragma unroll 8
      for (int e = 0; e < 32; ++e) {
        const float4 a = ((const float4*)fi)[e];
        const float4 b = ((const float4*)fj)[e];
        d  += a.x*b.x + a.y*b.y + a.z*b.z + a.w*b.w;
        si += a.x*a.x + a.y*a.y + a.z*a.z + a.w*a.w;
        sj += b.x*b.x + b.y*b.y + b.z*b.z + b.w*b.w;
      }
      pd[m][q] = d; psi[m][q] = si; psj[m][q] = sj;
    }
    __syncthreads();
    for (int m = threadIdx.x; m < nc; m += 256) {
      const float d  = pd[m][0]  + pd[m][1]  + pd[m][2]  + pd[m][3];
      const float si = psi[m][0] + psi[m][1] + psi[m][2] + psi[m][3];
      const float sj = psj[m][0] + psj[m][1] + psj[m][2] + psj[m][3];
      nd[posc[m]] = sqrtf(fmaxf(si + sj - 2.0f * d, 1e-11f));
    }
  }
}

// ---- K2: per-class gathered Gram, M-SPLIT: 2 blocks/class (r13 verbatim) -
__global__ __launch_bounds__(256) void k_cls(const u16* __restrict__ Fb,
    const float* __restrict__ sq, const float* __restrict__ nd,
    const int* __restrict__ cc, const int* __restrict__ pos,
    float* __restrict__ accf, float* __restrict__ out) {
  const int c = blockIdx.x >> 1, half = blockIdx.x & 1;
  __shared__ __align__(16) u16 P[128 * 512];     // 128 KB: full class tile
  __shared__ int posc[128];
  __shared__ float red[4];
  const int tid = threadIdx.x, wid = tid >> 6, lane = tid & 63;
  const int nc = cc[c];
  if (tid < 128) posc[tid] = pos[c * 128 + tid];
  __syncthreads();
  if (nc >= 2 && half * 64 < nc) {               // uniform branch per block
    const int wr = half, wc = wid;               // wave grid: 1 x 4
    const int r16 = lane & 15, gg = lane >> 4;
    const char* fb = (const char*)Fb;

    // stage: wave wid covers rows wid*32..wid*32+31; one instr = one row
    // (64 lanes x 16B). lane l -> LDS granule l, global granule l^(s&7).
    #pragma unroll 8
    for (int s = 0; s < 32; ++s) {
      const int row = wid * 32 + s;
      const int gr = posc[row];
      __builtin_amdgcn_global_load_lds(
          (const AS1 void*)(fb + (size_t)gr * 1024 + ((lane ^ (s & 7)) << 4)),
          (AS3 void*)(&P[row * 512]), 16, 0, 0);
    }

    f32x4 acc[4][2];
    #pragma unroll
    for (int m = 0; m < 4; ++m)
      #pragma unroll
      for (int n = 0; n < 2; ++n)
        #pragma unroll
        for (int q = 0; q < 4; ++q) acc[m][n][q] = 0.0f;

    __syncthreads();                             // one vmcnt(0) drain total
    #pragma unroll 4
    for (int t = 0; t < 16; ++t) {               // K = 16 x 32
      short8 af[4], bf[2];
      #pragma unroll
      for (int m = 0; m < 4; ++m) {
        const int row = wr * 64 + m * 16 + r16;
        const int gl = (t * 4 + gg) ^ (row & 7);
        af[m] = *(const short8*)&P[row * 512 + gl * 8];
      }
      #pragma unroll
      for (int n = 0; n < 2; ++n) {
        const int row = wc * 32 + n * 16 + r16;
        const int gl = (t * 4 + gg) ^ (row & 7);
        bf[n] = *(const short8*)&P[row * 512 + gl * 8];
      }
      #pragma unroll
      for (int m = 0; m < 4; ++m)
        #pragma unroll
        for (int n = 0; n < 2; ++n)
          acc[m][n] = __builtin_amdgcn_mfma_f32_16x16x32_bf16(af[m], bf[n], acc[m][n], 0, 0, 0);
    }

    // epilogue: hinge over valid (mi != nj, both < nc) ordered pairs
    float lsum = 0.0f;
    int njv[2]; float sqj[2];
    #pragma unroll
    for (int n = 0; n < 2; ++n) {
      const int nj = wc * 32 + n * 16 + r16;
      njv[n] = nj; sqj[n] = sq[posc[nj]];
    }
    #pragma unroll
    for (int m = 0; m < 4; ++m) {
      #pragma unroll
      for (int q = 0; q < 4; ++q) {
        const int mi = wr * 64 + m * 16 + gg * 4 + q;   // C/D: row=(lane>>4)*4+q
        const int i = posc[mi];
        const float sqi = sq[i], ndi = nd[i];
        const bool vi = mi < nc;
        #pragma unroll
        for (int n = 0; n < 2; ++n) {
          const float g = acc[m][n][q];
          const float dist = sqrtf(fmaxf(sqi + sqj[n] - 2.0f * g, 1e-11f));
          if (vi & (njv[n] < nc) & (mi != njv[n]))
            lsum += fmaxf(1.0f + dist - ndi, 0.0f);     // nd=inf -> 0 automatically
        }
      }
    }
    #pragma unroll
    for (int o = 32; o; o >>= 1) lsum += __shfl_xor(lsum, o);
    if (lane == 0) red[wid] = lsum;
    __syncthreads();
    if (tid == 0) atomicAdd(accf, red[0] + red[1] + red[2] + red[3]);
  }
  // pair-count (half 0 only) + last-block finalize (atomics only)
  if (tid == 0) {
    int* cnt  = (int*)accf + 1;
    int* done = (int*)accf + 2;
    if (half == 0 && nc < NN) atomicAdd(cnt, nc * (nc - 1));
    __threadfence();
    if (atomicAdd(done, 1) == 2 * NC - 1) {
      const float tot = atomicAdd(accf, 0.0f);    // atomic read
      const int n = atomicAdd(cnt, 0);            // atomic read
      out[0] = tot / (float)n;
    }
  }
}

extern "C" void kernel_launch(void* const* d_in, const int* in_sizes, int n_in,
                              void* d_out, int out_size, void* d_ws, size_t ws_size,
                              hipStream_t stream) {
  const float* F = (const float*)d_in[0];
  const int* labels = (const int*)d_in[1];   // harness materializes integers as int32
  const float* negu = (const float*)d_in[2];
  char* ws = (char*)d_ws;
  u16*   Fb    = (u16*)(ws + FB_OFF);
  float* sq    = (float*)(ws + SQ_OFF);
  float* nd    = (float*)(ws + ND_OFF);
  float* accf  = (float*)(ws + ACC_OFF);
  int*   cc    = (int*)(ws + CC_OFF);
  int*   pos   = (int*)(ws + POS_OFF);

  k_pn <<<NC + 2048, 256, 0, stream>>>(F, labels, negu, Fb, sq, cc, pos, nd, (int*)accf);
  k_cls<<<2 * NC,    256, 0, stream>>>(Fb, sq, nd, cc, pos, accf, (float*)d_out);
}

// Round 15
// 35.455 us; speedup vs baseline: 1.2800x; 1.2800x over previous
//
#include <hip/hip_runtime.h>
#include <hip/hip_bf16.h>
#include <cstdint>

#define NN 8192
#define DD 512
#define NC 128      // number of classes

typedef unsigned short u16;
typedef __attribute__((ext_vector_type(8))) short short8;
typedef __attribute__((ext_vector_type(4))) float f32x4;

#define AS1 __attribute__((address_space(1)))
#define AS3 __attribute__((address_space(3)))

// workspace layout (bytes)
#define FB_OFF   ((size_t)0)                      // bf16 features: NN*DD*2 = 8 MB
#define SQ_OFF   (FB_OFF + (size_t)NN*DD*2)       // fp32 sq norms: NN*4
#define ACC_OFF  (SQ_OFF + (size_t)NN*4)          // total(f32)@+0, cnt(int)@+4, done(int)@+8
#define CC_OFF   (ACC_OFF + 64)                   // class counts: NC*4
#define POS_OFF  (CC_OFF + 1024)                  // ordered member positions: NC*128*4

// ---- K1: fused {sq norms + bf16 cast + acc zero} | {per-class positions} --
// blocks 0..2047: prep (reads F only; writes Fb, sq). block 0 zeroes the
// accumulator line (NO atomics anywhere in this kernel -> plain stores
// flushed at kernel end, before k_cls's atomics — r9-verified pattern).
// blocks 2048..2175: classpos (reads labels only; writes cc, pos).
__global__ __launch_bounds__(256) void k_pc(const float* __restrict__ F,
    const int* __restrict__ labels, u16* __restrict__ Fb,
    float* __restrict__ sq, int* __restrict__ cc, int* __restrict__ pos,
    int* __restrict__ accz) {
  const int wid = threadIdx.x >> 6, lane = threadIdx.x & 63;
  if (blockIdx.x < 2048) {               // ---------------- prep half
    if (blockIdx.x == 0 && threadIdx.x < 16) accz[threadIdx.x] = 0;
    const int row = blockIdx.x * 4 + wid;
    const float* fr = F + (size_t)row * DD + lane * 8;
    float4 v0 = *(const float4*)fr;
    float4 v1 = *(const float4*)(fr + 4);
    float s = v0.x*v0.x + v0.y*v0.y + v0.z*v0.z + v0.w*v0.w
            + v1.x*v1.x + v1.y*v1.y + v1.z*v1.z + v1.w*v1.w;
    #pragma unroll
    for (int o = 32; o; o >>= 1) s += __shfl_xor(s, o);
    float t[8] = {v0.x, v0.y, v0.z, v0.w, v1.x, v1.y, v1.z, v1.w};
    unsigned p[8];
    #pragma unroll
    for (int e = 0; e < 8; ++e) {   // RNE fp32->bf16
      unsigned b = __float_as_uint(t[e]);
      b += 0x7fffu + ((b >> 16) & 1u);
      p[e] = b >> 16;
    }
    uint4 w;
    w.x = p[0] | (p[1] << 16); w.y = p[2] | (p[3] << 16);
    w.z = p[4] | (p[5] << 16); w.w = p[6] | (p[7] << 16);
    *(uint4*)(Fb + (size_t)row * DD + lane * 8) = w;
    if (lane == 0) sq[row] = s;
  } else {                               // ---------------- classpos half
    const int c = blockIdx.x - 2048;
    __shared__ int wcnt[4], woff[4];
    const int base0 = wid * 2048;
    int cw = 0;
    for (int b = 0; b < 2048; b += 64)   // pass 1: count
      cw += __popcll(__ballot(labels[base0 + b + lane] == c));
    if (lane == 0) wcnt[wid] = cw;
    __syncthreads();
    if (threadIdx.x == 0) {
      int o = 0;
      #pragma unroll
      for (int w = 0; w < 4; ++w) { woff[w] = o; o += wcnt[w]; }
      cc[c] = o;
    }
    __syncthreads();
    int off = woff[wid];
    for (int b = 0; b < 2048; b += 64) { // pass 2: emit (ascending order)
      const int idx = base0 + b + lane;
      const int hit = (labels[idx] == c);
      const unsigned long long m = __ballot(hit);
      if (hit) pos[c * 128 + off + __popcll(m & ((1ull << lane) - 1ull))] = idx;
      off += __popcll(m);
    }
    __syncthreads();
    const int nc = cc[c];
    for (int t = nc + threadIdx.x; t < 128; t += 256) pos[c * 128 + t] = 0;
  }
}

// ---- K2: per-class Gram (M-split, 2 blocks/class) + IN-FLIGHT nd ---------
// r13 k_cls + fused negative-distance for this half's 64 anchors:
// rank = 7-step binary search on monotone posc[t]-t (same t* as the
// verified ballot formula); dot = 4 quarter-threads/member, 256 independent
// 512B streams issued while the 128 KB staging drains (T14 regime).
__global__ __launch_bounds__(256) void k_cls(const u16* __restrict__ Fb,
    const float* __restrict__ F, const float* __restrict__ sq,
    const float* __restrict__ negu, const int* __restrict__ cc,
    const int* __restrict__ pos, float* __restrict__ accf,
    float* __restrict__ out) {
  const int c = blockIdx.x >> 1, half = blockIdx.x & 1;
  __shared__ __align__(16) u16 P[128 * 512];     // 128 KB: full class tile
  __shared__ int posc[128], jm[64];
  __shared__ float pd[64][4], ndc[64];
  __shared__ float red[4];
  const int tid = threadIdx.x, wid = tid >> 6, lane = tid & 63;
  const int nc = cc[c];
  if (tid < 128) posc[tid] = pos[c * 128 + tid];
  __syncthreads();
  if (nc >= 2 && half * 64 < nc) {               // uniform branch per block
    const int wr = half, wc = wid;               // wave grid: 1 x 4
    const int r16 = lane & 15, gg = lane >> 4;
    const char* fb = (const char*)Fb;

    // stage: wave wid covers rows wid*32..wid*32+31; one instr = one row
    // (64 lanes x 16B). lane l -> LDS granule l, global granule l^(s&7).
    #pragma unroll 8
    for (int s = 0; s < 32; ++s) {
      const int row = wid * 32 + s;
      const int gr = posc[row];
      __builtin_amdgcn_global_load_lds(
          (const AS1 void*)(fb + (size_t)gr * 1024 + ((lane ^ (s & 7)) << 4)),
          (AS3 void*)(&P[row * 512]), 16, 0, 0);
    }

    // ---- in-flight nd for this half's 64 anchors (thread = member,quarter)
    {
      const int ml = tid >> 2, q = tid & 3;
      const int row = half * 64 + ml;
      if (row < nc) {
        const int i = posc[row];
        const int n_neg = NN - nc;
        int k = (int)floorf(negu[i] * (float)n_neg);  // exact fp32 replica
        k = k < 0 ? 0 : (k > n_neg - 1 ? n_neg - 1 : k);
        int lo = 0, hi = nc;                     // t* = #{t: posc[t]-t <= k}
        while (lo < hi) {
          const int mid = (lo + hi) >> 1;
          if (posc[mid] - mid <= k) lo = mid + 1; else hi = mid;
        }
        const int j = k + lo;
        if (q == 0) jm[ml] = j;
        const float* fi = F + (size_t)i * DD + q * 128;
        const float* fj = F + (size_t)j * DD + q * 128;
        float d = 0.0f;
        #pragma unroll 8
        for (int e = 0; e < 32; ++e) {
          const float4 a = ((const float4*)fi)[e];
          const float4 b = ((const float4*)fj)[e];
          d += a.x*b.x + a.y*b.y + a.z*b.z + a.w*b.w;
        }
        pd[ml][q] = d;
      }
    }

    f32x4 acc[4][2];
    #pragma unroll
    for (int m = 0; m < 4; ++m)
      #pragma unroll
      for (int n = 0; n < 2; ++n)
        #pragma unroll
        for (int q = 0; q < 4; ++q) acc[m][n][q] = 0.0f;

    __syncthreads();                             // staging + pd/jm done
    if (tid < 64) {                              // finalize ndc (LDS-local)
      const int row = half * 64 + tid;
      if (row < nc) {
        const float d = pd[tid][0] + pd[tid][1] + pd[tid][2] + pd[tid][3];
        ndc[tid] = sqrtf(fmaxf(sq[posc[row]] + sq[jm[tid]] - 2.0f * d, 1e-11f));
      } else ndc[tid] = __builtin_inff();
    }

    #pragma unroll 4
    for (int t = 0; t < 16; ++t) {               // K = 16 x 32
      short8 af[4], bf[2];
      #pragma unroll
      for (int m = 0; m < 4; ++m) {
        const int row = wr * 64 + m * 16 + r16;
        const int gl = (t * 4 + gg) ^ (row & 7);
        af[m] = *(const short8*)&P[row * 512 + gl * 8];
      }
      #pragma unroll
      for (int n = 0; n < 2; ++n) {
        const int row = wc * 32 + n * 16 + r16;
        const int gl = (t * 4 + gg) ^ (row & 7);
        bf[n] = *(const short8*)&P[row * 512 + gl * 8];
      }
      #pragma unroll
      for (int m = 0; m < 4; ++m)
        #pragma unroll
        for (int n = 0; n < 2; ++n)
          acc[m][n] = __builtin_amdgcn_mfma_f32_16x16x32_bf16(af[m], bf[n], acc[m][n], 0, 0, 0);
    }
    __syncthreads();                             // ndc visible to all waves

    // epilogue: hinge over valid (mi != nj, both < nc) ordered pairs
    float lsum = 0.0f;
    int njv[2]; float sqj[2];
    #pragma unroll
    for (int n = 0; n < 2; ++n) {
      const int nj = wc * 32 + n * 16 + r16;
      njv[n] = nj; sqj[n] = sq[posc[nj]];
    }
    #pragma unroll
    for (int m = 0; m < 4; ++m) {
      #pragma unroll
      for (int q = 0; q < 4; ++q) {
        const int mi = wr * 64 + m * 16 + gg * 4 + q;   // C/D: row=(lane>>4)*4+q
        const float sqi = sq[posc[mi]];
        const float ndi = ndc[mi - half * 64];
        const bool vi = mi < nc;
        #pragma unroll
        for (int n = 0; n < 2; ++n) {
          const float g = acc[m][n][q];
          const float dist = sqrtf(fmaxf(sqi + sqj[n] - 2.0f * g, 1e-11f));
          if (vi & (njv[n] < nc) & (mi != njv[n]))
            lsum += fmaxf(1.0f + dist - ndi, 0.0f);     // nd=inf -> 0 automatically
        }
      }
    }
    #pragma unroll
    for (int o = 32; o; o >>= 1) lsum += __shfl_xor(lsum, o);
    if (lane == 0) red[wid] = lsum;
    __syncthreads();
    if (tid == 0) atomicAdd(accf, red[0] + red[1] + red[2] + red[3]);
  }
  // pair-count (half 0 only) + last-block finalize (atomics only)
  if (tid == 0) {
    int* cnt  = (int*)accf + 1;
    int* done = (int*)accf + 2;
    if (half == 0 && nc < NN) atomicAdd(cnt, nc * (nc - 1));
    __threadfence();
    if (atomicAdd(done, 1) == 2 * NC - 1) {
      const float tot = atomicAdd(accf, 0.0f);    // atomic read
      const int n = atomicAdd(cnt, 0);            // atomic read
      out[0] = tot / (float)n;
    }
  }
}

extern "C" void kernel_launch(void* const* d_in, const int* in_sizes, int n_in,
                              void* d_out, int out_size, void* d_ws, size_t ws_size,
                              hipStream_t stream) {
  const float* F = (const float*)d_in[0];
  const int* labels = (const int*)d_in[1];   // harness materializes integers as int32
  const float* negu = (const float*)d_in[2];
  char* ws = (char*)d_ws;
  u16*   Fb    = (u16*)(ws + FB_OFF);
  float* sq    = (float*)(ws + SQ_OFF);
  float* accf  = (float*)(ws + ACC_OFF);
  int*   cc    = (int*)(ws + CC_OFF);
  int*   pos   = (int*)(ws + POS_OFF);

  k_pc <<<2048 + NC, 256, 0, stream>>>(F, labels, Fb, sq, cc, pos, (int*)accf);
  k_cls<<<2 * NC,    256, 0, stream>>>(Fb, F, sq, negu, cc, pos, accf, (float*)d_out);
}

// Round 16
// 33.503 us; speedup vs baseline: 1.3546x; 1.0583x over previous
//
#include <hip/hip_runtime.h>
#include <hip/hip_bf16.h>
#include <cstdint>

#define NN 8192
#define DD 512
#define NC 128      // number of classes

typedef unsigned short u16;
typedef __attribute__((ext_vector_type(8))) short short8;
typedef __attribute__((ext_vector_type(4))) float f32x4;

#define AS1 __attribute__((address_space(1)))
#define AS3 __attribute__((address_space(3)))

__device__ __forceinline__ float bf2f(short x) {
  return __uint_as_float(((unsigned)(unsigned short)x) << 16);
}

// workspace layout (bytes)
#define FB_OFF   ((size_t)0)                      // bf16 features: NN*DD*2 = 8 MB
#define SQ_OFF   (FB_OFF + (size_t)NN*DD*2)       // fp32 sq norms: NN*4
#define ACC_OFF  (SQ_OFF + (size_t)NN*4)          // total(f32)@+0, cnt(int)@+4, done(int)@+8
#define CC_OFF   (ACC_OFF + 64)                   // class counts: NC*4
#define POS_OFF  (CC_OFF + 1024)                  // ordered member positions: NC*128*4

// ---- K1: fused {sq norms + bf16 cast + acc zero} | {per-class positions} --
// blocks 0..2047: prep (reads F only; writes Fb, sq). block 0 zeroes the
// accumulator line (NO atomics anywhere in this kernel -> plain stores
// flushed at kernel end, before k_cls's atomics — r9-verified pattern).
// blocks 2048..2175: classpos (reads labels only; writes cc, pos).
__global__ __launch_bounds__(256) void k_pc(const float* __restrict__ F,
    const int* __restrict__ labels, u16* __restrict__ Fb,
    float* __restrict__ sq, int* __restrict__ cc, int* __restrict__ pos,
    int* __restrict__ accz) {
  const int wid = threadIdx.x >> 6, lane = threadIdx.x & 63;
  if (blockIdx.x < 2048) {               // ---------------- prep half
    if (blockIdx.x == 0 && threadIdx.x < 16) accz[threadIdx.x] = 0;
    const int row = blockIdx.x * 4 + wid;
    const float* fr = F + (size_t)row * DD + lane * 8;
    float4 v0 = *(const float4*)fr;
    float4 v1 = *(const float4*)(fr + 4);
    float s = v0.x*v0.x + v0.y*v0.y + v0.z*v0.z + v0.w*v0.w
            + v1.x*v1.x + v1.y*v1.y + v1.z*v1.z + v1.w*v1.w;
    #pragma unroll
    for (int o = 32; o; o >>= 1) s += __shfl_xor(s, o);
    float t[8] = {v0.x, v0.y, v0.z, v0.w, v1.x, v1.y, v1.z, v1.w};
    unsigned p[8];
    #pragma unroll
    for (int e = 0; e < 8; ++e) {   // RNE fp32->bf16
      unsigned b = __float_as_uint(t[e]);
      b += 0x7fffu + ((b >> 16) & 1u);
      p[e] = b >> 16;
    }
    uint4 w;
    w.x = p[0] | (p[1] << 16); w.y = p[2] | (p[3] << 16);
    w.z = p[4] | (p[5] << 16); w.w = p[6] | (p[7] << 16);
    *(uint4*)(Fb + (size_t)row * DD + lane * 8) = w;
    if (lane == 0) sq[row] = s;
  } else {                               // ---------------- classpos half
    const int c = blockIdx.x - 2048;
    __shared__ int wcnt[4], woff[4];
    const int base0 = wid * 2048;
    int cw = 0;
    for (int b = 0; b < 2048; b += 64)   // pass 1: count
      cw += __popcll(__ballot(labels[base0 + b + lane] == c));
    if (lane == 0) wcnt[wid] = cw;
    __syncthreads();
    if (threadIdx.x == 0) {
      int o = 0;
      #pragma unroll
      for (int w = 0; w < 4; ++w) { woff[w] = o; o += wcnt[w]; }
      cc[c] = o;
    }
    __syncthreads();
    int off = woff[wid];
    for (int b = 0; b < 2048; b += 64) { // pass 2: emit (ascending order)
      const int idx = base0 + b + lane;
      const int hit = (labels[idx] == c);
      const unsigned long long m = __ballot(hit);
      if (hit) pos[c * 128 + off + __popcll(m & ((1ull << lane) - 1ull))] = idx;
      off += __popcll(m);
    }
    __syncthreads();
    const int nc = cc[c];
    for (int t = nc + threadIdx.x; t < 128; t += 256) pos[c * 128 + t] = 0;
  }
}

// ---- K2: per-class Gram (M-split) + in-flight bf16 nd --------------------
// XCD pairing: c = bid&127, half = bid>>7 -> a class's two blocks land on
// the same XCD (round-robin dispatch) so the second stage of the SAME
// 128 KB tile hits XCD-local L2. nd dots read Fb (bf16, same lines as
// staging). sq gathered once into LDS.
__global__ __launch_bounds__(256) void k_cls(const u16* __restrict__ Fb,
    const float* __restrict__ sq, const float* __restrict__ negu,
    const int* __restrict__ cc, const int* __restrict__ pos,
    float* __restrict__ accf, float* __restrict__ out) {
  const int c = blockIdx.x & 127, half = blockIdx.x >> 7;
  __shared__ __align__(16) u16 P[128 * 512];     // 128 KB: full class tile
  __shared__ int posc[128], jm[64];
  __shared__ float pd[64][4], ndc[64], sqc[128];
  __shared__ float red[4];
  const int tid = threadIdx.x, wid = tid >> 6, lane = tid & 63;
  const int nc = cc[c];
  if (tid < 128) posc[tid] = pos[c * 128 + tid];
  __syncthreads();
  if (nc >= 2 && half * 64 < nc) {               // uniform branch per block
    const int wr = half, wc = wid;               // wave grid: 1 x 4
    const int r16 = lane & 15, gg = lane >> 4;
    const char* fb = (const char*)Fb;

    // stage: wave wid covers rows wid*32..wid*32+31; one instr = one row
    // (64 lanes x 16B). lane l -> LDS granule l, global granule l^(s&7).
    #pragma unroll 8
    for (int s = 0; s < 32; ++s) {
      const int row = wid * 32 + s;
      const int gr = posc[row];
      __builtin_amdgcn_global_load_lds(
          (const AS1 void*)(fb + (size_t)gr * 1024 + ((lane ^ (s & 7)) << 4)),
          (AS3 void*)(&P[row * 512]), 16, 0, 0);
    }

    if (tid < 128) sqc[tid] = sq[posc[tid]];     // sq gather -> LDS

    // ---- in-flight nd for this half's 64 anchors (thread = member,quarter)
    // bf16 dot from Fb (same lines staging pulls); fp32 accumulate.
    {
      const int ml = tid >> 2, q = tid & 3;
      const int row = half * 64 + ml;
      if (row < nc) {
        const int i = posc[row];
        const int n_neg = NN - nc;
        int k = (int)floorf(negu[i] * (float)n_neg);  // exact fp32 replica
        k = k < 0 ? 0 : (k > n_neg - 1 ? n_neg - 1 : k);
        int lo = 0, hi = nc;                     // t* = #{t: posc[t]-t <= k}
        while (lo < hi) {
          const int mid = (lo + hi) >> 1;
          if (posc[mid] - mid <= k) lo = mid + 1; else hi = mid;
        }
        const int j = k + lo;
        if (q == 0) jm[ml] = j;
        const u16* fi = Fb + (size_t)i * DD + q * 128;
        const u16* fj = Fb + (size_t)j * DD + q * 128;
        float d = 0.0f;
        #pragma unroll 4
        for (int e = 0; e < 16; ++e) {
          const short8 a = ((const short8*)fi)[e];
          const short8 b = ((const short8*)fj)[e];
          #pragma unroll
          for (int x = 0; x < 8; ++x) d += bf2f(a[x]) * bf2f(b[x]);
        }
        pd[ml][q] = d;
      }
    }

    f32x4 acc[4][2];
    #pragma unroll
    for (int m = 0; m < 4; ++m)
      #pragma unroll
      for (int n = 0; n < 2; ++n)
        #pragma unroll
        for (int q = 0; q < 4; ++q) acc[m][n][q] = 0.0f;

    __syncthreads();                             // staging + pd/jm/sqc done
    if (tid < 64) {                              // finalize ndc (LDS-local)
      const int row = half * 64 + tid;
      if (row < nc) {
        const float d = pd[tid][0] + pd[tid][1] + pd[tid][2] + pd[tid][3];
        ndc[tid] = sqrtf(fmaxf(sqc[row] + sq[jm[tid]] - 2.0f * d, 1e-11f));
      } else ndc[tid] = __builtin_inff();
    }

    #pragma unroll 4
    for (int t = 0; t < 16; ++t) {               // K = 16 x 32
      short8 af[4], bf[2];
      #pragma unroll
      for (int m = 0; m < 4; ++m) {
        const int row = wr * 64 + m * 16 + r16;
        const int gl = (t * 4 + gg) ^ (row & 7);
        af[m] = *(const short8*)&P[row * 512 + gl * 8];
      }
      #pragma unroll
      for (int n = 0; n < 2; ++n) {
        const int row = wc * 32 + n * 16 + r16;
        const int gl = (t * 4 + gg) ^ (row & 7);
        bf[n] = *(const short8*)&P[row * 512 + gl * 8];
      }
      #pragma unroll
      for (int m = 0; m < 4; ++m)
        #pragma unroll
        for (int n = 0; n < 2; ++n)
          acc[m][n] = __builtin_amdgcn_mfma_f32_16x16x32_bf16(af[m], bf[n], acc[m][n], 0, 0, 0);
    }
    __syncthreads();                             // ndc visible to all waves

    // epilogue: hinge over valid (mi != nj, both < nc) ordered pairs
    float lsum = 0.0f;
    int njv[2]; float sqj[2];
    #pragma unroll
    for (int n = 0; n < 2; ++n) {
      const int nj = wc * 32 + n * 16 + r16;
      njv[n] = nj; sqj[n] = sqc[nj];
    }
    #pragma unroll
    for (int m = 0; m < 4; ++m) {
      #pragma unroll
      for (int q = 0; q < 4; ++q) {
        const int mi = wr * 64 + m * 16 + gg * 4 + q;   // C/D: row=(lane>>4)*4+q
        const float sqi = sqc[mi];
        const float ndi = ndc[mi - half * 64];
        const bool vi = mi < nc;
        #pragma unroll
        for (int n = 0; n < 2; ++n) {
          const float g = acc[m][n][q];
          const float dist = sqrtf(fmaxf(sqi + sqj[n] - 2.0f * g, 1e-11f));
          if (vi & (njv[n] < nc) & (mi != njv[n]))
            lsum += fmaxf(1.0f + dist - ndi, 0.0f);     // nd=inf -> 0 automatically
        }
      }
    }
    #pragma unroll
    for (int o = 32; o; o >>= 1) lsum += __shfl_xor(lsum, o);
    if (lane == 0) red[wid] = lsum;
    __syncthreads();
    if (tid == 0) atomicAdd(accf, red[0] + red[1] + red[2] + red[3]);
  }
  // pair-count (half 0 only) + last-block finalize (atomics only)
  if (tid == 0) {
    int* cnt  = (int*)accf + 1;
    int* done = (int*)accf + 2;
    if (half == 0 && nc < NN) atomicAdd(cnt, nc * (nc - 1));
    __threadfence();
    if (atomicAdd(done, 1) == 2 * NC - 1) {
      const float tot = atomicAdd(accf, 0.0f);    // atomic read
      const int n = atomicAdd(cnt, 0);            // atomic read
      out[0] = tot / (float)n;
    }
  }
}

extern "C" void kernel_launch(void* const* d_in, const int* in_sizes, int n_in,
                              void* d_out, int out_size, void* d_ws, size_t ws_size,
                              hipStream_t stream) {
  const float* F = (const float*)d_in[0];
  const int* labels = (const int*)d_in[1];   // harness materializes integers as int32
  const float* negu = (const float*)d_in[2];
  char* ws = (char*)d_ws;
  u16*   Fb    = (u16*)(ws + FB_OFF);
  float* sq    = (float*)(ws + SQ_OFF);
  float* accf  = (float*)(ws + ACC_OFF);
  int*   cc    = (int*)(ws + CC_OFF);
  int*   pos   = (int*)(ws + POS_OFF);

  k_pc <<<2048 + NC, 256, 0, stream>>>(F, labels, Fb, sq, cc, pos, (int*)accf);
  k_cls<<<2 * NC,    256, 0, stream>>>(Fb, sq, negu, cc, pos, accf, (float*)d_out);
}